// Round 8
// baseline (175.461 us; speedup 1.0000x reference)
//
#include <hip/hip_runtime.h>
#include <hip/hip_bf16.h>

typedef _Float16 f16;
typedef _Float16 f16x8 __attribute__((ext_vector_type(8)));
typedef float f32x4 __attribute__((ext_vector_type(4)));

#define NB 8
#define NT 2048
#define NE 1024
#define NH 64

#define CHUNKS_PER_BATCH 144   // sum over qi=0..31 of ceil((qi+1)/4)
#define MAXC 8                 // max chunks per q-row

// ws layout (bytes)
#define OFF_WT 0
#define OFF_QH 393216
#define OFF_KH 2490368
#define OFF_VT 4587520
#define OFF_ML 6684672          // 16384*8 float2  = 1 MiB
#define OFF_OP 7733248          // 16384*8*64 f16  = 16 MiB

// ---------------- kernel 0: weight convert + transpose (coalesced) -------
__global__ __launch_bounds__(256) void wconv_kernel(
        const float* __restrict__ Wk, const float* __restrict__ Wq,
        const float* __restrict__ Wv, f16* __restrict__ wt) {
    __shared__ float tile[64][65];
    const int mat = blockIdx.x >> 4;
    const int e0 = (blockIdx.x & 15) * 64;
    const float* W = (mat == 0) ? Wq : (mat == 1) ? Wk : Wv;
    const int tx = threadIdx.x & 63;
    const int ty = threadIdx.x >> 6;
#pragma unroll
    for (int r = ty; r < 64; r += 4)
        tile[r][tx] = W[(size_t)(e0 + r) * NH + tx];
    __syncthreads();
#pragma unroll
    for (int h = ty; h < 64; h += 4)
        wt[(size_t)mat * (NH * NE) + (size_t)h * NE + e0 + tx] = (f16)tile[tx][h];
}

// ---------------- kernel 1: QKV projection, LDS-staged pipeline ----------
__global__ __launch_bounds__(256) void qkv_proj_kernel(
        const float* __restrict__ x, const f16* __restrict__ wt,
        f16* __restrict__ Qh, f16* __restrict__ Kh, f16* __restrict__ VT) {
    __shared__ f16 xs[2][64 * 64];     // 8 KB per buf
    __shared__ f16 wsb[2][192 * 64];   // 24 KB per buf

    const int tid = threadIdx.x;
    const int wave = tid >> 6;
    const int lane = tid & 63;
    const int lr = lane & 15;
    const int lg = lane >> 4;
    const int m0 = blockIdx.x * 64;
    const int nt0 = wave * 3;

    f32x4 acc[12] = {};   // [mt*3 + j]

    float4 xr0, xr1, xr2, xr3;
    int4 wr0, wr1, wr2, wr3, wr4, wr5;

    const int xrow = tid >> 2;
    const int xcg = (tid & 3) * 16;

#define ISSUE_LOADS(kc)                                                        \
    do {                                                                       \
        const float* xb = x + (size_t)(m0 + xrow) * NE + (kc) + xcg;           \
        xr0 = *(const float4*)(xb);                                            \
        xr1 = *(const float4*)(xb + 4);                                        \
        xr2 = *(const float4*)(xb + 8);                                        \
        xr3 = *(const float4*)(xb + 12);                                       \
        wr0 = *(const int4*)(wt + (size_t)((tid + 0 * 256) >> 3) * NE + (kc) + ((tid + 0 * 256) & 7) * 8); \
        wr1 = *(const int4*)(wt + (size_t)((tid + 1 * 256) >> 3) * NE + (kc) + ((tid + 1 * 256) & 7) * 8); \
        wr2 = *(const int4*)(wt + (size_t)((tid + 2 * 256) >> 3) * NE + (kc) + ((tid + 2 * 256) & 7) * 8); \
        wr3 = *(const int4*)(wt + (size_t)((tid + 3 * 256) >> 3) * NE + (kc) + ((tid + 3 * 256) & 7) * 8); \
        wr4 = *(const int4*)(wt + (size_t)((tid + 4 * 256) >> 3) * NE + (kc) + ((tid + 4 * 256) & 7) * 8); \
        wr5 = *(const int4*)(wt + (size_t)((tid + 5 * 256) >> 3) * NE + (kc) + ((tid + 5 * 256) & 7) * 8); \
    } while (0)

#define CVT8(dst, a0, a1)                                                      \
    f16x8 dst = { (f16)a0.x, (f16)a0.y, (f16)a0.z, (f16)a0.w,                  \
                  (f16)a1.x, (f16)a1.y, (f16)a1.z, (f16)a1.w }

#define WRITE_LDS(buf)                                                         \
    do {                                                                       \
        { CVT8(v0, xr0, xr1);                                                  \
          int c = (tid & 3) * 2;                                               \
          int byo = xrow * 128 + ((c * 16) ^ ((xrow & 7) << 4));               \
          *(f16x8*)((char*)xs[buf] + byo) = v0; }                              \
        { CVT8(v1, xr2, xr3);                                                  \
          int c = (tid & 3) * 2 + 1;                                           \
          int byo = xrow * 128 + ((c * 16) ^ ((xrow & 7) << 4));               \
          *(f16x8*)((char*)xs[buf] + byo) = v1; }                              \
        { int jw = tid + 0 * 256, n = jw >> 3, c = jw & 7;                     \
          *(int4*)((char*)wsb[buf] + n * 128 + ((c * 16) ^ ((n & 7) << 4))) = wr0; } \
        { int jw = tid + 1 * 256, n = jw >> 3, c = jw & 7;                     \
          *(int4*)((char*)wsb[buf] + n * 128 + ((c * 16) ^ ((n & 7) << 4))) = wr1; } \
        { int jw = tid + 2 * 256, n = jw >> 3, c = jw & 7;                     \
          *(int4*)((char*)wsb[buf] + n * 128 + ((c * 16) ^ ((n & 7) << 4))) = wr2; } \
        { int jw = tid + 3 * 256, n = jw >> 3, c = jw & 7;                     \
          *(int4*)((char*)wsb[buf] + n * 128 + ((c * 16) ^ ((n & 7) << 4))) = wr3; } \
        { int jw = tid + 4 * 256, n = jw >> 3, c = jw & 7;                     \
          *(int4*)((char*)wsb[buf] + n * 128 + ((c * 16) ^ ((n & 7) << 4))) = wr4; } \
        { int jw = tid + 5 * 256, n = jw >> 3, c = jw & 7;                     \
          *(int4*)((char*)wsb[buf] + n * 128 + ((c * 16) ^ ((n & 7) << 4))) = wr5; } \
    } while (0)

    ISSUE_LOADS(0);
    WRITE_LDS(0);
    __syncthreads();

    int cur = 0;
    for (int c = 0; c < 16; ++c) {
        if (c < 15) ISSUE_LOADS((c + 1) * 64);

#pragma unroll
        for (int ks = 0; ks < 2; ++ks) {
            f16x8 af[4], bf[3];
#pragma unroll
            for (int mt = 0; mt < 4; ++mt) {
                int row = mt * 16 + lr;
                int byo = row * 128 + ((ks * 64 + lg * 16) ^ ((row & 7) << 4));
                af[mt] = *(const f16x8*)((const char*)xs[cur] + byo);
            }
#pragma unroll
            for (int j = 0; j < 3; ++j) {
                int n = (nt0 + j) * 16 + lr;
                int byo = n * 128 + ((ks * 64 + lg * 16) ^ ((n & 7) << 4));
                bf[j] = *(const f16x8*)((const char*)wsb[cur] + byo);
            }
#pragma unroll
            for (int mt = 0; mt < 4; ++mt)
#pragma unroll
                for (int j = 0; j < 3; ++j)
                    acc[mt * 3 + j] = __builtin_amdgcn_mfma_f32_16x16x32_f16(
                        af[mt], bf[j], acc[mt * 3 + j], 0, 0, 0);
        }

        __syncthreads();
        if (c < 15) {
            WRITE_LDS(cur ^ 1);
            __syncthreads();
        }
        cur ^= 1;
    }

#pragma unroll
    for (int j = 0; j < 3; ++j) {
        int nbase = (nt0 + j) * 16;
        int mat = nbase >> 6;
        int ncol = (nbase & 63) + lr;
#pragma unroll
        for (int mt = 0; mt < 4; ++mt) {
#pragma unroll
            for (int r = 0; r < 4; ++r) {
                int m = m0 + mt * 16 + lg * 4 + r;
                f16 val = (f16)acc[mt * 3 + j][r];
                if (mat == 0) {
                    Qh[(size_t)m * NH + ncol] = val;
                } else if (mat == 1) {
                    Kh[(size_t)m * NH + ncol] = val;
                } else {
                    int bb = m >> 11;
                    int tt = m & 2047;
                    VT[((size_t)bb * NH + ncol) * NT + tt] = val;
                }
            }
        }
    }
#undef ISSUE_LOADS
#undef CVT8
#undef WRITE_LDS
}

// ---------------- kernel 2: causal flash attention, split-KV, KVBLK=64 ---
// grid = NB * CHUNKS_PER_BATCH; block: 64 q rows (4 waves x 16), <=4 pair-steps
__global__ __launch_bounds__(256) void attn_part_kernel(
        const f16* __restrict__ Qh, const f16* __restrict__ Kh,
        const f16* __restrict__ VT, f16* __restrict__ op, float2* __restrict__ ml) {
    __shared__ f16 pbuf[4][16][72];   // [16 q][64 keys], padded

    const int wave = threadIdx.x >> 6;
    const int lane = threadIdx.x & 63;
    const int lr = lane & 15;
    const int lg = lane >> 4;

    const int b = blockIdx.x / CHUNKS_PER_BATCH;
    int c = blockIdx.x % CHUNKS_PER_BATCH;
    int qi = 0;
    for (; qi < 32; ++qi) {
        int ncq = (qi + 4) >> 2;
        if (c < ncq) break;
        c -= ncq;
    }
    const int total_steps = (qi + 1) * 2;       // 32-key units (always even)
    const int sbeg = c * 8;
    const int send = min(sbeg + 8, total_steps);
    const int qbase = qi * 64;
    const int qrow = qbase + wave * 16;

    const f16* Qb = Qh + (size_t)b * NT * NH;
    const f16* Kb = Kh + (size_t)b * NT * NH;
    const f16* Vb = VT + (size_t)b * NH * NT;

    // Q fragments, pre-scaled by 1/sqrt(64)=0.125 (power of 2: exact in f16)
    f16x8 qf[2];
#pragma unroll
    for (int h = 0; h < 2; ++h) {
        qf[h] = *(const f16x8*)(Qb + (size_t)(qrow + lr) * NH + h * 32 + lg * 8);
#pragma unroll
        for (int j = 0; j < 8; ++j) qf[h][j] = qf[h][j] * (f16)0.125f;
    }

    f32x4 o[4] = {};
    float mrow[4], lrow[4];
#pragma unroll
    for (int r = 0; r < 4; ++r) { mrow[r] = -INFINITY; lrow[r] = 0.f; }

    // 64-key pair-steps
    for (int s2 = sbeg; s2 < send; s2 += 2) {
        const int s0 = s2 * 32;

        // ---- QK^T: 4 tiles of 16q x 16keys (keys s0..s0+63)
        f32x4 S[4] = {};
#pragma unroll
        for (int t = 0; t < 4; ++t) {
#pragma unroll
            for (int h = 0; h < 2; ++h) {
                f16x8 kf = *(const f16x8*)(Kb + (size_t)(s0 + t * 16 + lr) * NH + h * 32 + lg * 8);
                S[t] = __builtin_amdgcn_mfma_f32_16x16x32_f16(qf[h], kf, S[t], 0, 0, 0);
            }
        }

        // ---- causal mask only when the 64-key span can touch the diagonal
        if (s0 + 63 > qrow) {
#pragma unroll
            for (int t = 0; t < 4; ++t) {
#pragma unroll
                for (int r = 0; r < 4; ++r) {
                    int q = qrow + lg * 4 + r;
                    int key = s0 + t * 16 + lr;
                    S[t][r] = (key <= q) ? S[t][r] : -INFINITY;
                }
            }
        }

        // ---- row max over 64 keys (local over 4 tiles, then 16-lane reduce)
        float mx[4];
#pragma unroll
        for (int r = 0; r < 4; ++r)
            mx[r] = fmaxf(fmaxf(S[0][r], S[1][r]), fmaxf(S[2][r], S[3][r]));
#pragma unroll
        for (int d = 1; d < 16; d <<= 1) {
#pragma unroll
            for (int r = 0; r < 4; ++r) mx[r] = fmaxf(mx[r], __shfl_xor(mx[r], d));
        }

        // ---- defer-max: skip rescale when no row's max grew (exp(0)=1 exact)
        float nms[4];
        bool grow = false;
#pragma unroll
        for (int r = 0; r < 4; ++r) grow = grow || (mx[r] > mrow[r]);
        if (__ballot(grow) != 0ull) {
#pragma unroll
            for (int r = 0; r < 4; ++r) {
                float nm = fmaxf(mrow[r], mx[r]);
                nms[r] = (nm == -INFINITY) ? 0.f : nm;
                float fr = __expf(mrow[r] - nms[r]);
                mrow[r] = nm;
                lrow[r] *= fr;
#pragma unroll
                for (int ht = 0; ht < 4; ++ht) o[ht][r] *= fr;
            }
        } else {
#pragma unroll
            for (int r = 0; r < 4; ++r) nms[r] = (mrow[r] == -INFINITY) ? 0.f : mrow[r];
        }

        // ---- p = exp(S - m), row sum, l update
#pragma unroll
        for (int t = 0; t < 4; ++t) {
#pragma unroll
            for (int r = 0; r < 4; ++r) S[t][r] = __expf(S[t][r] - nms[r]);
        }
#pragma unroll
        for (int r = 0; r < 4; ++r) {
            float rsum = (S[0][r] + S[1][r]) + (S[2][r] + S[3][r]);
#pragma unroll
            for (int d = 1; d < 16; d <<= 1) rsum += __shfl_xor(rsum, d);
            lrow[r] += rsum;
        }

        // ---- P -> LDS (C/D layout) -> A layout
#pragma unroll
        for (int t = 0; t < 4; ++t) {
#pragma unroll
            for (int r = 0; r < 4; ++r)
                pbuf[wave][lg * 4 + r][t * 16 + lr] = (f16)S[t][r];
        }
        __builtin_amdgcn_wave_barrier();
        f16x8 pf0 = *(const f16x8*)(&pbuf[wave][lr][lg * 8]);
        f16x8 pf1 = *(const f16x8*)(&pbuf[wave][lr][32 + lg * 8]);

        // ---- PV over 64 keys
#pragma unroll
        for (int ht = 0; ht < 4; ++ht) {
            f16x8 vf0 = *(const f16x8*)(Vb + (size_t)(ht * 16 + lr) * NT + s0 + lg * 8);
            f16x8 vf1 = *(const f16x8*)(Vb + (size_t)(ht * 16 + lr) * NT + s0 + 32 + lg * 8);
            o[ht] = __builtin_amdgcn_mfma_f32_16x16x32_f16(pf0, vf0, o[ht], 0, 0, 0);
            o[ht] = __builtin_amdgcn_mfma_f32_16x16x32_f16(pf1, vf1, o[ht], 0, 0, 0);
        }
        __builtin_amdgcn_wave_barrier();
    }

    // ---- write partials (unnormalized o, running m/l)
#pragma unroll
    for (int r = 0; r < 4; ++r) {
        int qt = qrow + lg * 4 + r;
        size_t slot = ((size_t)b * NT + qt) * MAXC + c;
#pragma unroll
        for (int ht = 0; ht < 4; ++ht)
            op[slot * NH + ht * 16 + lr] = (f16)o[ht][r];
        if (lr == 0) {
            float2 v; v.x = mrow[r]; v.y = lrow[r];
            ml[slot] = v;
        }
    }
}

// ---------------- kernel 3: combine split-KV partials --------------------
__global__ __launch_bounds__(256) void combine_kernel(
        const f16* __restrict__ op, const float2* __restrict__ ml,
        float* __restrict__ out) {
    int gid = blockIdx.x * 256 + threadIdx.x;
    int row = gid >> 6;
    int h = gid & 63;
    int q = row & (NT - 1);
    int qi = q >> 6;
    int nc = (qi + 4) >> 2;

    size_t base = (size_t)row * MAXC;
    float2 ml0 = ml[base];
    float M = ml0.x, L = ml0.y;
    float O = (float)op[base * NH + h];
    for (int cc = 1; cc < nc; ++cc) {
        float2 mlc = ml[base + cc];
        if (mlc.x == -INFINITY) continue;
        float oc = (float)op[(base + cc) * NH + h];
        float nM = fmaxf(M, mlc.x);
        float wo = __expf(M - nM), wc = __expf(mlc.x - nM);
        O = O * wo + oc * wc;
        L = L * wo + mlc.y * wc;
        M = nM;
    }
    out[gid] = O / L;
}

extern "C" void kernel_launch(void* const* d_in, const int* in_sizes, int n_in,
                              void* d_out, int out_size, void* d_ws, size_t ws_size,
                              hipStream_t stream) {
    const float* x  = (const float*)d_in[0];
    const float* Wk = (const float*)d_in[1];
    const float* Wq = (const float*)d_in[2];
    const float* Wv = (const float*)d_in[3];
    float* out = (float*)d_out;

    char* ws = (char*)d_ws;
    f16* wt    = (f16*)(ws + OFF_WT);
    f16* Qh    = (f16*)(ws + OFF_QH);
    f16* Kh    = (f16*)(ws + OFF_KH);
    f16* VT    = (f16*)(ws + OFF_VT);
    float2* ml = (float2*)(ws + OFF_ML);
    f16* op    = (f16*)(ws + OFF_OP);

    hipLaunchKernelGGL(wconv_kernel, dim3(48), dim3(256), 0, stream, Wk, Wq, Wv, wt);
    hipLaunchKernelGGL(qkv_proj_kernel, dim3(256), dim3(256), 0, stream, x, wt, Qh, Kh, VT);
    hipLaunchKernelGGL(attn_part_kernel, dim3(NB * CHUNKS_PER_BATCH), dim3(256), 0, stream,
                       Qh, Kh, VT, op, ml);
    hipLaunchKernelGGL(combine_kernel, dim3(NB * NT * NH / 256), dim3(256), 0, stream,
                       op, ml, out);
}

// Round 9
// 171.326 us; speedup vs baseline: 1.0241x; 1.0241x over previous
//
#include <hip/hip_runtime.h>
#include <hip/hip_bf16.h>

typedef _Float16 f16;
typedef _Float16 f16x8 __attribute__((ext_vector_type(8)));
typedef float f32x4 __attribute__((ext_vector_type(4)));

#define NB 8
#define NT 2048
#define NE 1024
#define NH 64

#define CHUNKS_PER_BATCH 144   // sum over qi=0..31 of ceil((qi+1)/4)
#define MAXC 8                 // max chunks per q-row

// ws layout (bytes)
#define OFF_WT 0
#define OFF_QH 393216
#define OFF_KH 2490368
#define OFF_VT 4587520
#define OFF_ML 6684672          // 16384*8 float2  = 1 MiB
#define OFF_OP 7733248          // 16384*8*64 f16  = 16 MiB

// ---------------- kernel 0: weight convert + transpose (coalesced) -------
__global__ __launch_bounds__(256) void wconv_kernel(
        const float* __restrict__ Wk, const float* __restrict__ Wq,
        const float* __restrict__ Wv, f16* __restrict__ wt) {
    __shared__ float tile[64][65];
    const int mat = blockIdx.x >> 4;
    const int e0 = (blockIdx.x & 15) * 64;
    const float* W = (mat == 0) ? Wq : (mat == 1) ? Wk : Wv;
    const int tx = threadIdx.x & 63;
    const int ty = threadIdx.x >> 6;
#pragma unroll
    for (int r = ty; r < 64; r += 4)
        tile[r][tx] = W[(size_t)(e0 + r) * NH + tx];
    __syncthreads();
#pragma unroll
    for (int h = ty; h < 64; h += 4)
        wt[(size_t)mat * (NH * NE) + (size_t)h * NE + e0 + tx] = (f16)tile[tx][h];
}

// ---------------- kernel 1: QKV projection, LDS-staged pipeline ----------
__global__ __launch_bounds__(256) void qkv_proj_kernel(
        const float* __restrict__ x, const f16* __restrict__ wt,
        f16* __restrict__ Qh, f16* __restrict__ Kh, f16* __restrict__ VT) {
    __shared__ f16 xs[2][64 * 64];     // 8 KB per buf
    __shared__ f16 wsb[2][192 * 64];   // 24 KB per buf

    const int tid = threadIdx.x;
    const int wave = tid >> 6;
    const int lane = tid & 63;
    const int lr = lane & 15;
    const int lg = lane >> 4;
    const int m0 = blockIdx.x * 64;
    const int nt0 = wave * 3;

    f32x4 acc[12] = {};   // [mt*3 + j]

    float4 xr0, xr1, xr2, xr3;
    int4 wr0, wr1, wr2, wr3, wr4, wr5;

    const int xrow = tid >> 2;
    const int xcg = (tid & 3) * 16;

#define ISSUE_LOADS(kc)                                                        \
    do {                                                                       \
        const float* xb = x + (size_t)(m0 + xrow) * NE + (kc) + xcg;           \
        xr0 = *(const float4*)(xb);                                            \
        xr1 = *(const float4*)(xb + 4);                                        \
        xr2 = *(const float4*)(xb + 8);                                        \
        xr3 = *(const float4*)(xb + 12);                                       \
        wr0 = *(const int4*)(wt + (size_t)((tid + 0 * 256) >> 3) * NE + (kc) + ((tid + 0 * 256) & 7) * 8); \
        wr1 = *(const int4*)(wt + (size_t)((tid + 1 * 256) >> 3) * NE + (kc) + ((tid + 1 * 256) & 7) * 8); \
        wr2 = *(const int4*)(wt + (size_t)((tid + 2 * 256) >> 3) * NE + (kc) + ((tid + 2 * 256) & 7) * 8); \
        wr3 = *(const int4*)(wt + (size_t)((tid + 3 * 256) >> 3) * NE + (kc) + ((tid + 3 * 256) & 7) * 8); \
        wr4 = *(const int4*)(wt + (size_t)((tid + 4 * 256) >> 3) * NE + (kc) + ((tid + 4 * 256) & 7) * 8); \
        wr5 = *(const int4*)(wt + (size_t)((tid + 5 * 256) >> 3) * NE + (kc) + ((tid + 5 * 256) & 7) * 8); \
    } while (0)

#define CVT8(dst, a0, a1)                                                      \
    f16x8 dst = { (f16)a0.x, (f16)a0.y, (f16)a0.z, (f16)a0.w,                  \
                  (f16)a1.x, (f16)a1.y, (f16)a1.z, (f16)a1.w }

#define WRITE_LDS(buf)                                                         \
    do {                                                                       \
        { CVT8(v0, xr0, xr1);                                                  \
          int c = (tid & 3) * 2;                                               \
          int byo = xrow * 128 + ((c * 16) ^ ((xrow & 7) << 4));               \
          *(f16x8*)((char*)xs[buf] + byo) = v0; }                              \
        { CVT8(v1, xr2, xr3);                                                  \
          int c = (tid & 3) * 2 + 1;                                           \
          int byo = xrow * 128 + ((c * 16) ^ ((xrow & 7) << 4));               \
          *(f16x8*)((char*)xs[buf] + byo) = v1; }                              \
        { int jw = tid + 0 * 256, n = jw >> 3, c = jw & 7;                     \
          *(int4*)((char*)wsb[buf] + n * 128 + ((c * 16) ^ ((n & 7) << 4))) = wr0; } \
        { int jw = tid + 1 * 256, n = jw >> 3, c = jw & 7;                     \
          *(int4*)((char*)wsb[buf] + n * 128 + ((c * 16) ^ ((n & 7) << 4))) = wr1; } \
        { int jw = tid + 2 * 256, n = jw >> 3, c = jw & 7;                     \
          *(int4*)((char*)wsb[buf] + n * 128 + ((c * 16) ^ ((n & 7) << 4))) = wr2; } \
        { int jw = tid + 3 * 256, n = jw >> 3, c = jw & 7;                     \
          *(int4*)((char*)wsb[buf] + n * 128 + ((c * 16) ^ ((n & 7) << 4))) = wr3; } \
        { int jw = tid + 4 * 256, n = jw >> 3, c = jw & 7;                     \
          *(int4*)((char*)wsb[buf] + n * 128 + ((c * 16) ^ ((n & 7) << 4))) = wr4; } \
        { int jw = tid + 5 * 256, n = jw >> 3, c = jw & 7;                     \
          *(int4*)((char*)wsb[buf] + n * 128 + ((c * 16) ^ ((n & 7) << 4))) = wr5; } \
    } while (0)

    ISSUE_LOADS(0);
    WRITE_LDS(0);
    __syncthreads();

    int cur = 0;
    for (int c = 0; c < 16; ++c) {
        if (c < 15) ISSUE_LOADS((c + 1) * 64);

#pragma unroll
        for (int ks = 0; ks < 2; ++ks) {
            f16x8 af[4], bf[3];
#pragma unroll
            for (int mt = 0; mt < 4; ++mt) {
                int row = mt * 16 + lr;
                int byo = row * 128 + ((ks * 64 + lg * 16) ^ ((row & 7) << 4));
                af[mt] = *(const f16x8*)((const char*)xs[cur] + byo);
            }
#pragma unroll
            for (int j = 0; j < 3; ++j) {
                int n = (nt0 + j) * 16 + lr;
                int byo = n * 128 + ((ks * 64 + lg * 16) ^ ((n & 7) << 4));
                bf[j] = *(const f16x8*)((const char*)wsb[cur] + byo);
            }
#pragma unroll
            for (int mt = 0; mt < 4; ++mt)
#pragma unroll
                for (int j = 0; j < 3; ++j)
                    acc[mt * 3 + j] = __builtin_amdgcn_mfma_f32_16x16x32_f16(
                        af[mt], bf[j], acc[mt * 3 + j], 0, 0, 0);
        }

        __syncthreads();
        if (c < 15) {
            WRITE_LDS(cur ^ 1);
            __syncthreads();
        }
        cur ^= 1;
    }

#pragma unroll
    for (int j = 0; j < 3; ++j) {
        int nbase = (nt0 + j) * 16;
        int mat = nbase >> 6;
        int ncol = (nbase & 63) + lr;
#pragma unroll
        for (int mt = 0; mt < 4; ++mt) {
#pragma unroll
            for (int r = 0; r < 4; ++r) {
                int m = m0 + mt * 16 + lg * 4 + r;
                f16 val = (f16)acc[mt * 3 + j][r];
                if (mat == 0) {
                    Qh[(size_t)m * NH + ncol] = val;
                } else if (mat == 1) {
                    Kh[(size_t)m * NH + ncol] = val;
                } else {
                    int bb = m >> 11;
                    int tt = m & 2047;
                    VT[((size_t)bb * NH + ncol) * NT + tt] = val;
                }
            }
        }
    }
#undef ISSUE_LOADS
#undef CVT8
#undef WRITE_LDS
}

// ---------------- kernel 2: causal flash attention, split-KV, KVBLK=64 ---
// Register-pipelined: K double-buffered across pair-steps (A/B sets),
// V issued at step top so its latency hides under QK+softmax+transpose.
__global__ __launch_bounds__(256) void attn_part_kernel(
        const f16* __restrict__ Qh, const f16* __restrict__ Kh,
        const f16* __restrict__ VT, f16* __restrict__ op, float2* __restrict__ ml) {
    __shared__ f16 pbuf[4][16][72];   // [16 q][64 keys], padded

    const int wave = threadIdx.x >> 6;
    const int lane = threadIdx.x & 63;
    const int lr = lane & 15;
    const int lg = lane >> 4;

    const int b = blockIdx.x / CHUNKS_PER_BATCH;
    int c = blockIdx.x % CHUNKS_PER_BATCH;
    int qi = 0;
    for (; qi < 32; ++qi) {
        int ncq = (qi + 4) >> 2;
        if (c < ncq) break;
        c -= ncq;
    }
    const int total_steps = (qi + 1) * 2;       // 32-key units (always even)
    const int sbeg = c * 8;
    const int send = min(sbeg + 8, total_steps);
    const int qbase = qi * 64;
    const int qrow = qbase + wave * 16;

    const f16* Qb = Qh + (size_t)b * NT * NH;
    const f16* Kb = Kh + (size_t)b * NT * NH;
    const f16* Vb = VT + (size_t)b * NH * NT;

    // Q fragments, pre-scaled by 1/sqrt(64)=0.125 (power of 2: exact in f16)
    f16x8 qf[2];
#pragma unroll
    for (int h = 0; h < 2; ++h) {
        qf[h] = *(const f16x8*)(Qb + (size_t)(qrow + lr) * NH + h * 32 + lg * 8);
#pragma unroll
        for (int j = 0; j < 8; ++j) qf[h][j] = qf[h][j] * (f16)0.125f;
    }

    f32x4 o[4] = {};
    float mrow[4], lrow[4];
#pragma unroll
    for (int r = 0; r < 4; ++r) { mrow[r] = -INFINITY; lrow[r] = 0.f; }

    f16x8 kfA[8], kfB[8], vf[8];   // static-indexed only (full unroll)

#define ISSUE_K(KARR, s0_)                                                     \
    do {                                                                       \
        _Pragma("unroll")                                                      \
        for (int t = 0; t < 4; ++t) {                                          \
            _Pragma("unroll")                                                  \
            for (int h = 0; h < 2; ++h)                                        \
                KARR[t * 2 + h] = *(const f16x8*)(                             \
                    Kb + (size_t)((s0_) + t * 16 + lr) * NH + h * 32 + lg * 8);\
        }                                                                      \
    } while (0)

#define ISSUE_V(s0_)                                                           \
    do {                                                                       \
        _Pragma("unroll")                                                      \
        for (int t = 0; t < 4; ++t) {                                          \
            vf[t * 2 + 0] = *(const f16x8*)(                                   \
                Vb + (size_t)(t * 16 + lr) * NT + (s0_) + lg * 8);             \
            vf[t * 2 + 1] = *(const f16x8*)(                                   \
                Vb + (size_t)(t * 16 + lr) * NT + (s0_) + 32 + lg * 8);        \
        }                                                                      \
    } while (0)

#define STEP_COMPUTE(KARR, s0_)                                                \
    do {                                                                       \
        f32x4 S[4] = {};                                                       \
        _Pragma("unroll")                                                      \
        for (int t = 0; t < 4; ++t) {                                          \
            _Pragma("unroll")                                                  \
            for (int h = 0; h < 2; ++h)                                        \
                S[t] = __builtin_amdgcn_mfma_f32_16x16x32_f16(                 \
                    qf[h], KARR[t * 2 + h], S[t], 0, 0, 0);                    \
        }                                                                      \
        if ((s0_) + 63 > qrow) {                                               \
            _Pragma("unroll")                                                  \
            for (int t = 0; t < 4; ++t) {                                      \
                _Pragma("unroll")                                              \
                for (int r = 0; r < 4; ++r) {                                  \
                    int q = qrow + lg * 4 + r;                                 \
                    int key = (s0_) + t * 16 + lr;                             \
                    S[t][r] = (key <= q) ? S[t][r] : -INFINITY;                \
                }                                                              \
            }                                                                  \
        }                                                                      \
        float mx[4];                                                           \
        _Pragma("unroll")                                                      \
        for (int r = 0; r < 4; ++r)                                            \
            mx[r] = fmaxf(fmaxf(S[0][r], S[1][r]), fmaxf(S[2][r], S[3][r]));   \
        _Pragma("unroll")                                                      \
        for (int d = 1; d < 16; d <<= 1) {                                     \
            _Pragma("unroll")                                                  \
            for (int r = 0; r < 4; ++r) mx[r] = fmaxf(mx[r], __shfl_xor(mx[r], d)); \
        }                                                                      \
        float nms[4];                                                          \
        bool grow = false;                                                     \
        _Pragma("unroll")                                                      \
        for (int r = 0; r < 4; ++r) grow = grow || (mx[r] > mrow[r]);          \
        if (__ballot(grow) != 0ull) {                                          \
            _Pragma("unroll")                                                  \
            for (int r = 0; r < 4; ++r) {                                      \
                float nm = fmaxf(mrow[r], mx[r]);                              \
                nms[r] = (nm == -INFINITY) ? 0.f : nm;                         \
                float fr = __expf(mrow[r] - nms[r]);                           \
                mrow[r] = nm;                                                  \
                lrow[r] *= fr;                                                 \
                _Pragma("unroll")                                              \
                for (int ht = 0; ht < 4; ++ht) o[ht][r] *= fr;                 \
            }                                                                  \
        } else {                                                               \
            _Pragma("unroll")                                                  \
            for (int r = 0; r < 4; ++r)                                        \
                nms[r] = (mrow[r] == -INFINITY) ? 0.f : mrow[r];               \
        }                                                                      \
        _Pragma("unroll")                                                      \
        for (int t = 0; t < 4; ++t) {                                          \
            _Pragma("unroll")                                                  \
            for (int r = 0; r < 4; ++r) S[t][r] = __expf(S[t][r] - nms[r]);    \
        }                                                                      \
        _Pragma("unroll")                                                      \
        for (int r = 0; r < 4; ++r) {                                          \
            float rsum = (S[0][r] + S[1][r]) + (S[2][r] + S[3][r]);            \
            _Pragma("unroll")                                                  \
            for (int d = 1; d < 16; d <<= 1) rsum += __shfl_xor(rsum, d);      \
            lrow[r] += rsum;                                                   \
        }                                                                      \
        _Pragma("unroll")                                                      \
        for (int t = 0; t < 4; ++t) {                                          \
            _Pragma("unroll")                                                  \
            for (int r = 0; r < 4; ++r)                                        \
                pbuf[wave][lg * 4 + r][t * 16 + lr] = (f16)S[t][r];            \
        }                                                                      \
        __builtin_amdgcn_wave_barrier();                                       \
        f16x8 pf0 = *(const f16x8*)(&pbuf[wave][lr][lg * 8]);                  \
        f16x8 pf1 = *(const f16x8*)(&pbuf[wave][lr][32 + lg * 8]);             \
        _Pragma("unroll")                                                      \
        for (int ht = 0; ht < 4; ++ht) {                                       \
            o[ht] = __builtin_amdgcn_mfma_f32_16x16x32_f16(pf0, vf[ht * 2 + 0], o[ht], 0, 0, 0); \
            o[ht] = __builtin_amdgcn_mfma_f32_16x16x32_f16(pf1, vf[ht * 2 + 1], o[ht], 0, 0, 0); \
        }                                                                      \
        __builtin_amdgcn_wave_barrier();                                       \
    } while (0)

    int s2 = sbeg;
    ISSUE_K(kfA, s2 * 32);
    for (;;) {
        {   // body A: compute from kfA, prefetch into kfB
            const int s0 = s2 * 32;
            ISSUE_V(s0);
            if (s2 + 2 < send) ISSUE_K(kfB, (s2 + 2) * 32);
            STEP_COMPUTE(kfA, s0);
            s2 += 2;
            if (s2 >= send) break;
        }
        {   // body B: compute from kfB, prefetch into kfA
            const int s0 = s2 * 32;
            ISSUE_V(s0);
            if (s2 + 2 < send) ISSUE_K(kfA, (s2 + 2) * 32);
            STEP_COMPUTE(kfB, s0);
            s2 += 2;
            if (s2 >= send) break;
        }
    }
#undef ISSUE_K
#undef ISSUE_V
#undef STEP_COMPUTE

    // ---- write partials (unnormalized o, running m/l)
#pragma unroll
    for (int r = 0; r < 4; ++r) {
        int qt = qrow + lg * 4 + r;
        size_t slot = ((size_t)b * NT + qt) * MAXC + c;
#pragma unroll
        for (int ht = 0; ht < 4; ++ht)
            op[slot * NH + ht * 16 + lr] = (f16)o[ht][r];
        if (lr == 0) {
            float2 v; v.x = mrow[r]; v.y = lrow[r];
            ml[slot] = v;
        }
    }
}

// ---------------- kernel 3: combine split-KV partials --------------------
__global__ __launch_bounds__(256) void combine_kernel(
        const f16* __restrict__ op, const float2* __restrict__ ml,
        float* __restrict__ out) {
    int gid = blockIdx.x * 256 + threadIdx.x;
    int row = gid >> 6;
    int h = gid & 63;
    int q = row & (NT - 1);
    int qi = q >> 6;
    int nc = (qi + 4) >> 2;

    size_t base = (size_t)row * MAXC;
    float2 ml0 = ml[base];
    float M = ml0.x, L = ml0.y;
    float O = (float)op[base * NH + h];
    for (int cc = 1; cc < nc; ++cc) {
        float2 mlc = ml[base + cc];
        if (mlc.x == -INFINITY) continue;
        float oc = (float)op[(base + cc) * NH + h];
        float nM = fmaxf(M, mlc.x);
        float wo = __expf(M - nM), wc = __expf(mlc.x - nM);
        O = O * wo + oc * wc;
        L = L * wo + mlc.y * wc;
        M = nM;
    }
    out[gid] = O / L;
}

extern "C" void kernel_launch(void* const* d_in, const int* in_sizes, int n_in,
                              void* d_out, int out_size, void* d_ws, size_t ws_size,
                              hipStream_t stream) {
    const float* x  = (const float*)d_in[0];
    const float* Wk = (const float*)d_in[1];
    const float* Wq = (const float*)d_in[2];
    const float* Wv = (const float*)d_in[3];
    float* out = (float*)d_out;

    char* ws = (char*)d_ws;
    f16* wt    = (f16*)(ws + OFF_WT);
    f16* Qh    = (f16*)(ws + OFF_QH);
    f16* Kh    = (f16*)(ws + OFF_KH);
    f16* VT    = (f16*)(ws + OFF_VT);
    float2* ml = (float2*)(ws + OFF_ML);
    f16* op    = (f16*)(ws + OFF_OP);

    hipLaunchKernelGGL(wconv_kernel, dim3(48), dim3(256), 0, stream, Wk, Wq, Wv, wt);
    hipLaunchKernelGGL(qkv_proj_kernel, dim3(256), dim3(256), 0, stream, x, wt, Qh, Kh, VT);
    hipLaunchKernelGGL(attn_part_kernel, dim3(NB * CHUNKS_PER_BATCH), dim3(256), 0, stream,
                       Qh, Kh, VT, op, ml);
    hipLaunchKernelGGL(combine_kernel, dim3(NB * NT * NH / 256), dim3(256), 0, stream,
                       op, ml, out);
}

// Round 11
// 150.202 us; speedup vs baseline: 1.1682x; 1.1406x over previous
//
#include <hip/hip_runtime.h>
#include <hip/hip_bf16.h>

typedef _Float16 f16;
typedef _Float16 f16x8 __attribute__((ext_vector_type(8)));
typedef float f32x4 __attribute__((ext_vector_type(4)));

#define NB 8
#define NT 2048
#define NE 1024
#define NH 64

#define CHUNKS_PER_BATCH 144   // sum over qi=0..31 of ceil((qi+1)/4)
#define MAXC 8                 // max chunks per q-row

// ws layout (bytes)
#define OFF_WT 0
#define OFF_QH 393216
#define OFF_KH 2490368
#define OFF_VT 4587520
#define OFF_ML 6684672          // 16384*8 float2  = 1 MiB
#define OFF_OP 7733248          // 16384*8*64 f16  = 16 MiB

// ---------------- kernel 0: weight convert + transpose (coalesced) -------
__global__ __launch_bounds__(256) void wconv_kernel(
        const float* __restrict__ Wk, const float* __restrict__ Wq,
        const float* __restrict__ Wv, f16* __restrict__ wt) {
    __shared__ float tile[64][65];
    const int mat = blockIdx.x >> 4;
    const int e0 = (blockIdx.x & 15) * 64;
    const float* W = (mat == 0) ? Wq : (mat == 1) ? Wk : Wv;
    const int tx = threadIdx.x & 63;
    const int ty = threadIdx.x >> 6;
#pragma unroll
    for (int r = ty; r < 64; r += 4)
        tile[r][tx] = W[(size_t)(e0 + r) * NH + tx];
    __syncthreads();
#pragma unroll
    for (int h = ty; h < 64; h += 4)
        wt[(size_t)mat * (NH * NE) + (size_t)h * NE + e0 + tx] = (f16)tile[tx][h];
}

// ---------------- kernel 1: QKV projection, LDS-staged pipeline ----------
__global__ __launch_bounds__(256) void qkv_proj_kernel(
        const float* __restrict__ x, const f16* __restrict__ wt,
        f16* __restrict__ Qh, f16* __restrict__ Kh, f16* __restrict__ VT) {
    __shared__ f16 xs[2][64 * 64];     // 8 KB per buf
    __shared__ f16 wsb[2][192 * 64];   // 24 KB per buf

    const int tid = threadIdx.x;
    const int wave = tid >> 6;
    const int lane = tid & 63;
    const int lr = lane & 15;
    const int lg = lane >> 4;
    const int m0 = blockIdx.x * 64;
    const int nt0 = wave * 3;

    f32x4 acc[12] = {};   // [mt*3 + j]

    float4 xr0, xr1, xr2, xr3;
    int4 wr0, wr1, wr2, wr3, wr4, wr5;

    const int xrow = tid >> 2;
    const int xcg = (tid & 3) * 16;

#define ISSUE_LOADS(kc)                                                        \
    do {                                                                       \
        const float* xb = x + (size_t)(m0 + xrow) * NE + (kc) + xcg;           \
        xr0 = *(const float4*)(xb);                                            \
        xr1 = *(const float4*)(xb + 4);                                        \
        xr2 = *(const float4*)(xb + 8);                                        \
        xr3 = *(const float4*)(xb + 12);                                       \
        wr0 = *(const int4*)(wt + (size_t)((tid + 0 * 256) >> 3) * NE + (kc) + ((tid + 0 * 256) & 7) * 8); \
        wr1 = *(const int4*)(wt + (size_t)((tid + 1 * 256) >> 3) * NE + (kc) + ((tid + 1 * 256) & 7) * 8); \
        wr2 = *(const int4*)(wt + (size_t)((tid + 2 * 256) >> 3) * NE + (kc) + ((tid + 2 * 256) & 7) * 8); \
        wr3 = *(const int4*)(wt + (size_t)((tid + 3 * 256) >> 3) * NE + (kc) + ((tid + 3 * 256) & 7) * 8); \
        wr4 = *(const int4*)(wt + (size_t)((tid + 4 * 256) >> 3) * NE + (kc) + ((tid + 4 * 256) & 7) * 8); \
        wr5 = *(const int4*)(wt + (size_t)((tid + 5 * 256) >> 3) * NE + (kc) + ((tid + 5 * 256) & 7) * 8); \
    } while (0)

#define CVT8(dst, a0, a1)                                                      \
    f16x8 dst = { (f16)a0.x, (f16)a0.y, (f16)a0.z, (f16)a0.w,                  \
                  (f16)a1.x, (f16)a1.y, (f16)a1.z, (f16)a1.w }

#define WRITE_LDS(buf)                                                         \
    do {                                                                       \
        { CVT8(v0, xr0, xr1);                                                  \
          int c = (tid & 3) * 2;                                               \
          int byo = xrow * 128 + ((c * 16) ^ ((xrow & 7) << 4));               \
          *(f16x8*)((char*)xs[buf] + byo) = v0; }                              \
        { CVT8(v1, xr2, xr3);                                                  \
          int c = (tid & 3) * 2 + 1;                                           \
          int byo = xrow * 128 + ((c * 16) ^ ((xrow & 7) << 4));               \
          *(f16x8*)((char*)xs[buf] + byo) = v1; }                              \
        { int jw = tid + 0 * 256, n = jw >> 3, c = jw & 7;                     \
          *(int4*)((char*)wsb[buf] + n * 128 + ((c * 16) ^ ((n & 7) << 4))) = wr0; } \
        { int jw = tid + 1 * 256, n = jw >> 3, c = jw & 7;                     \
          *(int4*)((char*)wsb[buf] + n * 128 + ((c * 16) ^ ((n & 7) << 4))) = wr1; } \
        { int jw = tid + 2 * 256, n = jw >> 3, c = jw & 7;                     \
          *(int4*)((char*)wsb[buf] + n * 128 + ((c * 16) ^ ((n & 7) << 4))) = wr2; } \
        { int jw = tid + 3 * 256, n = jw >> 3, c = jw & 7;                     \
          *(int4*)((char*)wsb[buf] + n * 128 + ((c * 16) ^ ((n & 7) << 4))) = wr3; } \
        { int jw = tid + 4 * 256, n = jw >> 3, c = jw & 7;                     \
          *(int4*)((char*)wsb[buf] + n * 128 + ((c * 16) ^ ((n & 7) << 4))) = wr4; } \
        { int jw = tid + 5 * 256, n = jw >> 3, c = jw & 7;                     \
          *(int4*)((char*)wsb[buf] + n * 128 + ((c * 16) ^ ((n & 7) << 4))) = wr5; } \
    } while (0)

    ISSUE_LOADS(0);
    WRITE_LDS(0);
    __syncthreads();

    int cur = 0;
    for (int c = 0; c < 16; ++c) {
        if (c < 15) ISSUE_LOADS((c + 1) * 64);

#pragma unroll
        for (int ks = 0; ks < 2; ++ks) {
            f16x8 af[4], bf[3];
#pragma unroll
            for (int mt = 0; mt < 4; ++mt) {
                int row = mt * 16 + lr;
                int byo = row * 128 + ((ks * 64 + lg * 16) ^ ((row & 7) << 4));
                af[mt] = *(const f16x8*)((const char*)xs[cur] + byo);
            }
#pragma unroll
            for (int j = 0; j < 3; ++j) {
                int n = (nt0 + j) * 16 + lr;
                int byo = n * 128 + ((ks * 64 + lg * 16) ^ ((n & 7) << 4));
                bf[j] = *(const f16x8*)((const char*)wsb[cur] + byo);
            }
#pragma unroll
            for (int mt = 0; mt < 4; ++mt)
#pragma unroll
                for (int j = 0; j < 3; ++j)
                    acc[mt * 3 + j] = __builtin_amdgcn_mfma_f32_16x16x32_f16(
                        af[mt], bf[j], acc[mt * 3 + j], 0, 0, 0);
        }

        __syncthreads();
        if (c < 15) {
            WRITE_LDS(cur ^ 1);
            __syncthreads();
        }
        cur ^= 1;
    }

#pragma unroll
    for (int j = 0; j < 3; ++j) {
        int nbase = (nt0 + j) * 16;
        int mat = nbase >> 6;
        int ncol = (nbase & 63) + lr;
#pragma unroll
        for (int mt = 0; mt < 4; ++mt) {
#pragma unroll
            for (int r = 0; r < 4; ++r) {
                int m = m0 + mt * 16 + lg * 4 + r;
                f16 val = (f16)acc[mt * 3 + j][r];
                if (mat == 0) {
                    Qh[(size_t)m * NH + ncol] = val;
                } else if (mat == 1) {
                    Kh[(size_t)m * NH + ncol] = val;
                } else {
                    int bb = m >> 11;
                    int tt = m & 2047;
                    VT[((size_t)bb * NH + ncol) * NT + tt] = val;
                }
            }
        }
    }
#undef ISSUE_LOADS
#undef CVT8
#undef WRITE_LDS
}

// ---------------- kernel 2: causal flash attention, split-KV, KVBLK=64 ---
// Block-shared LDS staging of K/V tiles (double-buffered, XOR-swizzled),
// T14 order: issue next tile's global loads before compute, ds_write after.
__global__ __launch_bounds__(256) void attn_part_kernel(
        const f16* __restrict__ Qh, const f16* __restrict__ Kh,
        const f16* __restrict__ VT, f16* __restrict__ op, float2* __restrict__ ml) {
    __shared__ f16 kbuf[2][64 * 64];   // 8 KB per buf, rows=keys, cols=h
    __shared__ f16 vbuf[2][64 * 64];   // 8 KB per buf, rows=h, cols=keys
    __shared__ f16 pbuf[4][16][72];    // per-wave P transpose

    const int tid = threadIdx.x;
    const int wave = tid >> 6;
    const int lane = tid & 63;
    const int lr = lane & 15;
    const int lg = lane >> 4;

    const int b = blockIdx.x / CHUNKS_PER_BATCH;
    int c = blockIdx.x % CHUNKS_PER_BATCH;
    int qi = 0;
    for (; qi < 32; ++qi) {
        int ncq = (qi + 4) >> 2;
        if (c < ncq) break;
        c -= ncq;
    }
    const int total_steps = (qi + 1) * 2;       // 32-key units (always even)
    const int sbeg = c * 8;
    const int send = min(sbeg + 8, total_steps);
    const int nsteps = (send - sbeg) >> 1;      // 64-key pair-steps, uniform per block
    const int qbase = qi * 64;
    const int qrow = qbase + wave * 16;

    const f16* Qb = Qh + (size_t)b * NT * NH;
    const f16* Kb = Kh + (size_t)b * NT * NH;
    const f16* Vb = VT + (size_t)b * NH * NT;

    // staging geometry: 4 threads per row, 2x16B each
    const int srow = tid >> 2;              // 0..63
    const int scol = (tid & 3) * 16;        // f16 col
    const int scb0 = (tid & 3) * 32;        // byte col
    int4 kr0, kr1, vr0, vr1;

#define LOADKV(s0_)                                                            \
    do {                                                                       \
        const f16* kp = Kb + (size_t)((s0_) + srow) * NH + scol;               \
        kr0 = *(const int4*)(kp);                                              \
        kr1 = *(const int4*)(kp + 8);                                          \
        const f16* vp = Vb + (size_t)srow * NT + (s0_) + scol;                 \
        vr0 = *(const int4*)(vp);                                              \
        vr1 = *(const int4*)(vp + 8);                                          \
    } while (0)

#define WRITEKV(buf_)                                                          \
    do {                                                                       \
        int swz = (srow & 7) << 4;                                             \
        char* kb = (char*)kbuf[buf_] + srow * 128;                             \
        *(int4*)(kb + (scb0 ^ swz)) = kr0;                                     \
        *(int4*)(kb + ((scb0 + 16) ^ swz)) = kr1;                              \
        char* vb = (char*)vbuf[buf_] + srow * 128;                             \
        *(int4*)(vb + (scb0 ^ swz)) = vr0;                                     \
        *(int4*)(vb + ((scb0 + 16) ^ swz)) = vr1;                              \
    } while (0)

    // Q fragments, pre-scaled by 1/sqrt(64)=0.125 (power of 2: exact in f16)
    f16x8 qf[2];
#pragma unroll
    for (int h = 0; h < 2; ++h) {
        qf[h] = *(const f16x8*)(Qb + (size_t)(qrow + lr) * NH + h * 32 + lg * 8);
#pragma unroll
        for (int j = 0; j < 8; ++j) qf[h][j] = qf[h][j] * (f16)0.125f;
    }

    f32x4 o[4] = {};
    float mrow[4], lrow[4];
#pragma unroll
    for (int r = 0; r < 4; ++r) { mrow[r] = -INFINITY; lrow[r] = 0.f; }

    // prologue: stage first tile
    LOADKV(sbeg * 32);
    WRITEKV(0);

    int cur = 0;
    for (int n = 0; n < nsteps; ++n) {
        __syncthreads();   // buf[cur] visible to all waves
        const int s0 = (sbeg + 2 * n) * 32;
        if (n + 1 < nsteps) LOADKV((sbeg + 2 * (n + 1)) * 32);

        // ---- QK^T from kbuf: 4 tiles of 16q x 16keys
        f32x4 S[4] = {};
#pragma unroll
        for (int t = 0; t < 4; ++t) {
            int row = t * 16 + lr;
            const char* kb = (const char*)kbuf[cur] + row * 128;
            int swz = (row & 7) << 4;
#pragma unroll
            for (int h = 0; h < 2; ++h) {
                f16x8 kf = *(const f16x8*)(kb + ((h * 64 + lg * 16) ^ swz));
                S[t] = __builtin_amdgcn_mfma_f32_16x16x32_f16(qf[h], kf, S[t], 0, 0, 0);
            }
        }

        // ---- causal mask only when the 64-key span can touch the diagonal
        if (s0 + 63 > qrow) {
#pragma unroll
            for (int t = 0; t < 4; ++t) {
#pragma unroll
                for (int r = 0; r < 4; ++r) {
                    int q = qrow + lg * 4 + r;
                    int key = s0 + t * 16 + lr;
                    S[t][r] = (key <= q) ? S[t][r] : -INFINITY;
                }
            }
        }

        // ---- row max over 64 keys
        float mx[4];
#pragma unroll
        for (int r = 0; r < 4; ++r)
            mx[r] = fmaxf(fmaxf(S[0][r], S[1][r]), fmaxf(S[2][r], S[3][r]));
#pragma unroll
        for (int d = 1; d < 16; d <<= 1) {
#pragma unroll
            for (int r = 0; r < 4; ++r) mx[r] = fmaxf(mx[r], __shfl_xor(mx[r], d));
        }

        // ---- defer-max: skip rescale when no row's max grew (exp(0)=1 exact)
        float nms[4];
        bool grow = false;
#pragma unroll
        for (int r = 0; r < 4; ++r) grow = grow || (mx[r] > mrow[r]);
        if (__ballot(grow) != 0ull) {
#pragma unroll
            for (int r = 0; r < 4; ++r) {
                float nm = fmaxf(mrow[r], mx[r]);
                nms[r] = (nm == -INFINITY) ? 0.f : nm;
                float fr = __expf(mrow[r] - nms[r]);
                mrow[r] = nm;
                lrow[r] *= fr;
#pragma unroll
                for (int ht = 0; ht < 4; ++ht) o[ht][r] *= fr;
            }
        } else {
#pragma unroll
            for (int r = 0; r < 4; ++r) nms[r] = (mrow[r] == -INFINITY) ? 0.f : mrow[r];
        }

        // ---- p = exp(S - m), row sum, l update
#pragma unroll
        for (int t = 0; t < 4; ++t) {
#pragma unroll
            for (int r = 0; r < 4; ++r) S[t][r] = __expf(S[t][r] - nms[r]);
        }
#pragma unroll
        for (int r = 0; r < 4; ++r) {
            float rsum = (S[0][r] + S[1][r]) + (S[2][r] + S[3][r]);
#pragma unroll
            for (int d = 1; d < 16; d <<= 1) rsum += __shfl_xor(rsum, d);
            lrow[r] += rsum;
        }

        // ---- P -> LDS (C/D layout) -> A layout (wave-private pbuf)
#pragma unroll
        for (int t = 0; t < 4; ++t) {
#pragma unroll
            for (int r = 0; r < 4; ++r)
                pbuf[wave][lg * 4 + r][t * 16 + lr] = (f16)S[t][r];
        }
        __builtin_amdgcn_wave_barrier();
        f16x8 pf0 = *(const f16x8*)(&pbuf[wave][lr][lg * 8]);
        f16x8 pf1 = *(const f16x8*)(&pbuf[wave][lr][32 + lg * 8]);

        // ---- PV from vbuf over 64 keys
#pragma unroll
        for (int ht = 0; ht < 4; ++ht) {
            int row = ht * 16 + lr;
            const char* vb = (const char*)vbuf[cur] + row * 128;
            int swz = (row & 7) << 4;
            f16x8 vf0 = *(const f16x8*)(vb + ((lg * 16) ^ swz));
            f16x8 vf1 = *(const f16x8*)(vb + ((64 + lg * 16) ^ swz));
            o[ht] = __builtin_amdgcn_mfma_f32_16x16x32_f16(pf0, vf0, o[ht], 0, 0, 0);
            o[ht] = __builtin_amdgcn_mfma_f32_16x16x32_f16(pf1, vf1, o[ht], 0, 0, 0);
        }
        __builtin_amdgcn_wave_barrier();

        // ---- stage next tile into the other buffer (visible after next barrier)
        if (n + 1 < nsteps) WRITEKV(cur ^ 1);
        cur ^= 1;
    }
#undef LOADKV
#undef WRITEKV

    // ---- write partials (unnormalized o, running m/l)
#pragma unroll
    for (int r = 0; r < 4; ++r) {
        int qt = qrow + lg * 4 + r;
        size_t slot = ((size_t)b * NT + qt) * MAXC + c;
#pragma unroll
        for (int ht = 0; ht < 4; ++ht)
            op[slot * NH + ht * 16 + lr] = (f16)o[ht][r];
        if (lr == 0) {
            float2 v; v.x = mrow[r]; v.y = lrow[r];
            ml[slot] = v;
        }
    }
}

// ---------------- kernel 3: combine split-KV partials --------------------
__global__ __launch_bounds__(256) void combine_kernel(
        const f16* __restrict__ op, const float2* __restrict__ ml,
        float* __restrict__ out) {
    int gid = blockIdx.x * 256 + threadIdx.x;
    int row = gid >> 6;
    int h = gid & 63;
    int q = row & (NT - 1);
    int qi = q >> 6;
    int nc = (qi + 4) >> 2;

    size_t base = (size_t)row * MAXC;
    float2 ml0 = ml[base];
    float M = ml0.x, L = ml0.y;
    float O = (float)op[base * NH + h];
    for (int cc = 1; cc < nc; ++cc) {
        float2 mlc = ml[base + cc];
        if (mlc.x == -INFINITY) continue;
        float oc = (float)op[(base + cc) * NH + h];
        float nM = fmaxf(M, mlc.x);
        float wo = __expf(M - nM), wc = __expf(mlc.x - nM);
        O = O * wo + oc * wc;
        L = L * wo + mlc.y * wc;
        M = nM;
    }
    out[gid] = O / L;
}

extern "C" void kernel_launch(void* const* d_in, const int* in_sizes, int n_in,
                              void* d_out, int out_size, void* d_ws, size_t ws_size,
                              hipStream_t stream) {
    const float* x  = (const float*)d_in[0];
    const float* Wk = (const float*)d_in[1];
    const float* Wq = (const float*)d_in[2];
    const float* Wv = (const float*)d_in[3];
    float* out = (float*)d_out;

    char* ws = (char*)d_ws;
    f16* wt    = (f16*)(ws + OFF_WT);
    f16* Qh    = (f16*)(ws + OFF_QH);
    f16* Kh    = (f16*)(ws + OFF_KH);
    f16* VT    = (f16*)(ws + OFF_VT);
    float2* ml = (float2*)(ws + OFF_ML);
    f16* op    = (f16*)(ws + OFF_OP);

    hipLaunchKernelGGL(wconv_kernel, dim3(48), dim3(256), 0, stream, Wk, Wq, Wv, wt);
    hipLaunchKernelGGL(qkv_proj_kernel, dim3(256), dim3(256), 0, stream, x, wt, Qh, Kh, VT);
    hipLaunchKernelGGL(attn_part_kernel, dim3(NB * CHUNKS_PER_BATCH), dim3(256), 0, stream,
                       Qh, Kh, VT, op, ml);
    hipLaunchKernelGGL(combine_kernel, dim3(NB * NT * NH / 256), dim3(256), 0, stream,
                       op, ml, out);
}

// Round 12
// 145.682 us; speedup vs baseline: 1.2044x; 1.0310x over previous
//
#include <hip/hip_runtime.h>
#include <hip/hip_bf16.h>

typedef _Float16 f16;
typedef _Float16 f16x8 __attribute__((ext_vector_type(8)));
typedef float f32x4 __attribute__((ext_vector_type(4)));

#define NB 8
#define NT 2048
#define NE 1024
#define NH 64

#define CHUNKS_PER_BATCH 144   // sum over qi=0..31 of ceil((qi+1)/4)
#define MAXC 8                 // max chunks per q-row

// ws layout (bytes)
#define OFF_WT 0
#define OFF_QH 393216
#define OFF_KH 2490368
#define OFF_VT 4587520
#define OFF_ML 6684672          // 16384*8 float2  = 1 MiB
#define OFF_OP 7733248          // 16384*8*64 f16  = 16 MiB

// ---------------- kernel 0: weight convert + transpose (coalesced) -------
__global__ __launch_bounds__(256) void wconv_kernel(
        const float* __restrict__ Wk, const float* __restrict__ Wq,
        const float* __restrict__ Wv, f16* __restrict__ wt) {
    __shared__ float tile[64][65];
    const int mat = blockIdx.x >> 4;
    const int e0 = (blockIdx.x & 15) * 64;
    const float* W = (mat == 0) ? Wq : (mat == 1) ? Wk : Wv;
    const int tx = threadIdx.x & 63;
    const int ty = threadIdx.x >> 6;
#pragma unroll
    for (int r = ty; r < 64; r += 4)
        tile[r][tx] = W[(size_t)(e0 + r) * NH + tx];
    __syncthreads();
#pragma unroll
    for (int h = ty; h < 64; h += 4)
        wt[(size_t)mat * (NH * NE) + (size_t)h * NE + e0 + tx] = (f16)tile[tx][h];
}

// ---------------- kernel 1: QKV projection, LDS-staged pipeline ----------
// BM=32, BN=192, BK=64; 512 blocks x 4 waves -> 2 blocks/CU (barrier overlap).
__global__ __launch_bounds__(256) void qkv_proj_kernel(
        const float* __restrict__ x, const f16* __restrict__ wt,
        f16* __restrict__ Qh, f16* __restrict__ Kh, f16* __restrict__ VT) {
    __shared__ f16 xs[2][32 * 64];     // 4 KB per buf
    __shared__ f16 wsb[2][192 * 64];   // 24 KB per buf

    const int tid = threadIdx.x;
    const int wave = tid >> 6;
    const int lane = tid & 63;
    const int lr = lane & 15;
    const int lg = lane >> 4;
    const int m0 = blockIdx.x * 32;
    const int nt0 = wave * 3;

    f32x4 acc[6] = {};   // [mt*3 + j], mt in {0,1}

    float4 xr0, xr1;
    int4 wr0, wr1, wr2, wr3, wr4, wr5;

    const int xrow = tid >> 3;          // 0..31
    const int xc8 = (tid & 7) * 8;      // float col group (8 floats)

#define ISSUE_LOADS(kc)                                                        \
    do {                                                                       \
        const float* xb = x + (size_t)(m0 + xrow) * NE + (kc) + xc8;           \
        xr0 = *(const float4*)(xb);                                            \
        xr1 = *(const float4*)(xb + 4);                                        \
        wr0 = *(const int4*)(wt + (size_t)((tid + 0 * 256) >> 3) * NE + (kc) + ((tid + 0 * 256) & 7) * 8); \
        wr1 = *(const int4*)(wt + (size_t)((tid + 1 * 256) >> 3) * NE + (kc) + ((tid + 1 * 256) & 7) * 8); \
        wr2 = *(const int4*)(wt + (size_t)((tid + 2 * 256) >> 3) * NE + (kc) + ((tid + 2 * 256) & 7) * 8); \
        wr3 = *(const int4*)(wt + (size_t)((tid + 3 * 256) >> 3) * NE + (kc) + ((tid + 3 * 256) & 7) * 8); \
        wr4 = *(const int4*)(wt + (size_t)((tid + 4 * 256) >> 3) * NE + (kc) + ((tid + 4 * 256) & 7) * 8); \
        wr5 = *(const int4*)(wt + (size_t)((tid + 5 * 256) >> 3) * NE + (kc) + ((tid + 5 * 256) & 7) * 8); \
    } while (0)

#define WRITE_LDS(buf)                                                         \
    do {                                                                       \
        { f16x8 v0 = { (f16)xr0.x, (f16)xr0.y, (f16)xr0.z, (f16)xr0.w,         \
                       (f16)xr1.x, (f16)xr1.y, (f16)xr1.z, (f16)xr1.w };       \
          int byo = xrow * 128 + (((tid & 7) * 16) ^ ((xrow & 7) << 4));       \
          *(f16x8*)((char*)xs[buf] + byo) = v0; }                              \
        { int jw = tid + 0 * 256, n = jw >> 3, c = jw & 7;                     \
          *(int4*)((char*)wsb[buf] + n * 128 + ((c * 16) ^ ((n & 7) << 4))) = wr0; } \
        { int jw = tid + 1 * 256, n = jw >> 3, c = jw & 7;                     \
          *(int4*)((char*)wsb[buf] + n * 128 + ((c * 16) ^ ((n & 7) << 4))) = wr1; } \
        { int jw = tid + 2 * 256, n = jw >> 3, c = jw & 7;                     \
          *(int4*)((char*)wsb[buf] + n * 128 + ((c * 16) ^ ((n & 7) << 4))) = wr2; } \
        { int jw = tid + 3 * 256, n = jw >> 3, c = jw & 7;                     \
          *(int4*)((char*)wsb[buf] + n * 128 + ((c * 16) ^ ((n & 7) << 4))) = wr3; } \
        { int jw = tid + 4 * 256, n = jw >> 3, c = jw & 7;                     \
          *(int4*)((char*)wsb[buf] + n * 128 + ((c * 16) ^ ((n & 7) << 4))) = wr4; } \
        { int jw = tid + 5 * 256, n = jw >> 3, c = jw & 7;                     \
          *(int4*)((char*)wsb[buf] + n * 128 + ((c * 16) ^ ((n & 7) << 4))) = wr5; } \
    } while (0)

    ISSUE_LOADS(0);
    WRITE_LDS(0);
    __syncthreads();

    int cur = 0;
    for (int c = 0; c < 16; ++c) {
        if (c < 15) ISSUE_LOADS((c + 1) * 64);

#pragma unroll
        for (int ks = 0; ks < 2; ++ks) {
            f16x8 af[2], bf[3];
#pragma unroll
            for (int mt = 0; mt < 2; ++mt) {
                int row = mt * 16 + lr;
                int byo = row * 128 + ((ks * 64 + lg * 16) ^ ((row & 7) << 4));
                af[mt] = *(const f16x8*)((const char*)xs[cur] + byo);
            }
#pragma unroll
            for (int j = 0; j < 3; ++j) {
                int n = (nt0 + j) * 16 + lr;
                int byo = n * 128 + ((ks * 64 + lg * 16) ^ ((n & 7) << 4));
                bf[j] = *(const f16x8*)((const char*)wsb[cur] + byo);
            }
#pragma unroll
            for (int mt = 0; mt < 2; ++mt)
#pragma unroll
                for (int j = 0; j < 3; ++j)
                    acc[mt * 3 + j] = __builtin_amdgcn_mfma_f32_16x16x32_f16(
                        af[mt], bf[j], acc[mt * 3 + j], 0, 0, 0);
        }

        __syncthreads();
        if (c < 15) {
            WRITE_LDS(cur ^ 1);
            __syncthreads();
        }
        cur ^= 1;
    }

#pragma unroll
    for (int j = 0; j < 3; ++j) {
        int nbase = (nt0 + j) * 16;
        int mat = nbase >> 6;
        int ncol = (nbase & 63) + lr;
#pragma unroll
        for (int mt = 0; mt < 2; ++mt) {
#pragma unroll
            for (int r = 0; r < 4; ++r) {
                int m = m0 + mt * 16 + lg * 4 + r;
                f16 val = (f16)acc[mt * 3 + j][r];
                if (mat == 0) {
                    Qh[(size_t)m * NH + ncol] = val;
                } else if (mat == 1) {
                    Kh[(size_t)m * NH + ncol] = val;
                } else {
                    int bb = m >> 11;
                    int tt = m & 2047;
                    VT[((size_t)bb * NH + ncol) * NT + tt] = val;
                }
            }
        }
    }
#undef ISSUE_LOADS
#undef WRITE_LDS
}

// ---------------- kernel 2: causal flash attention, split-KV, KVBLK=64 ---
// Block-shared LDS staging of K/V tiles (double-buffered, XOR-swizzled).
__global__ __launch_bounds__(256) void attn_part_kernel(
        const f16* __restrict__ Qh, const f16* __restrict__ Kh,
        const f16* __restrict__ VT, f16* __restrict__ op, float2* __restrict__ ml) {
    __shared__ f16 kbuf[2][64 * 64];   // 8 KB per buf, rows=keys, cols=h
    __shared__ f16 vbuf[2][64 * 64];   // 8 KB per buf, rows=h, cols=keys
    __shared__ f16 pbuf[4][16][72];    // per-wave P transpose

    const int tid = threadIdx.x;
    const int wave = tid >> 6;
    const int lane = tid & 63;
    const int lr = lane & 15;
    const int lg = lane >> 4;

    const int b = blockIdx.x / CHUNKS_PER_BATCH;
    int c = blockIdx.x % CHUNKS_PER_BATCH;
    int qi = 0;
    for (; qi < 32; ++qi) {
        int ncq = (qi + 4) >> 2;
        if (c < ncq) break;
        c -= ncq;
    }
    const int total_steps = (qi + 1) * 2;       // 32-key units (always even)
    const int sbeg = c * 8;
    const int send = min(sbeg + 8, total_steps);
    const int nsteps = (send - sbeg) >> 1;      // 64-key pair-steps, uniform per block
    const int qbase = qi * 64;
    const int qrow = qbase + wave * 16;

    const f16* Qb = Qh + (size_t)b * NT * NH;
    const f16* Kb = Kh + (size_t)b * NT * NH;
    const f16* Vb = VT + (size_t)b * NH * NT;

    // staging geometry: 4 threads per row, 2x16B each
    const int srow = tid >> 2;              // 0..63
    const int scol = (tid & 3) * 16;        // f16 col
    const int scb0 = (tid & 3) * 32;        // byte col
    int4 kr0, kr1, vr0, vr1;

#define LOADKV(s0_)                                                            \
    do {                                                                       \
        const f16* kp = Kb + (size_t)((s0_) + srow) * NH + scol;               \
        kr0 = *(const int4*)(kp);                                              \
        kr1 = *(const int4*)(kp + 8);                                          \
        const f16* vp = Vb + (size_t)srow * NT + (s0_) + scol;                 \
        vr0 = *(const int4*)(vp);                                              \
        vr1 = *(const int4*)(vp + 8);                                          \
    } while (0)

#define WRITEKV(buf_)                                                          \
    do {                                                                       \
        int swz = (srow & 7) << 4;                                             \
        char* kb = (char*)kbuf[buf_] + srow * 128;                             \
        *(int4*)(kb + (scb0 ^ swz)) = kr0;                                     \
        *(int4*)(kb + ((scb0 + 16) ^ swz)) = kr1;                              \
        char* vb = (char*)vbuf[buf_] + srow * 128;                             \
        *(int4*)(vb + (scb0 ^ swz)) = vr0;                                     \
        *(int4*)(vb + ((scb0 + 16) ^ swz)) = vr1;                              \
    } while (0)

    // Q fragments, pre-scaled by 1/sqrt(64)=0.125 (power of 2: exact in f16)
    f16x8 qf[2];
#pragma unroll
    for (int h = 0; h < 2; ++h) {
        qf[h] = *(const f16x8*)(Qb + (size_t)(qrow + lr) * NH + h * 32 + lg * 8);
#pragma unroll
        for (int j = 0; j < 8; ++j) qf[h][j] = qf[h][j] * (f16)0.125f;
    }

    f32x4 o[4] = {};
    float mrow[4], lrow[4];
#pragma unroll
    for (int r = 0; r < 4; ++r) { mrow[r] = -INFINITY; lrow[r] = 0.f; }

    // prologue: stage first tile
    LOADKV(sbeg * 32);
    WRITEKV(0);

    int cur = 0;
    for (int n = 0; n < nsteps; ++n) {
        __syncthreads();   // buf[cur] visible to all waves
        const int s0 = (sbeg + 2 * n) * 32;
        if (n + 1 < nsteps) LOADKV((sbeg + 2 * (n + 1)) * 32);

        // ---- QK^T from kbuf: 4 tiles of 16q x 16keys
        f32x4 S[4] = {};
#pragma unroll
        for (int t = 0; t < 4; ++t) {
            int row = t * 16 + lr;
            const char* kb = (const char*)kbuf[cur] + row * 128;
            int swz = (row & 7) << 4;
#pragma unroll
            for (int h = 0; h < 2; ++h) {
                f16x8 kf = *(const f16x8*)(kb + ((h * 64 + lg * 16) ^ swz));
                S[t] = __builtin_amdgcn_mfma_f32_16x16x32_f16(qf[h], kf, S[t], 0, 0, 0);
            }
        }

        // ---- causal mask only when the 64-key span can touch the diagonal
        if (s0 + 63 > qrow) {
#pragma unroll
            for (int t = 0; t < 4; ++t) {
#pragma unroll
                for (int r = 0; r < 4; ++r) {
                    int q = qrow + lg * 4 + r;
                    int key = s0 + t * 16 + lr;
                    S[t][r] = (key <= q) ? S[t][r] : -INFINITY;
                }
            }
        }

        // ---- row max over 64 keys
        float mx[4];
#pragma unroll
        for (int r = 0; r < 4; ++r)
            mx[r] = fmaxf(fmaxf(S[0][r], S[1][r]), fmaxf(S[2][r], S[3][r]));
#pragma unroll
        for (int d = 1; d < 16; d <<= 1) {
#pragma unroll
            for (int r = 0; r < 4; ++r) mx[r] = fmaxf(mx[r], __shfl_xor(mx[r], d));
        }

        // ---- defer-max: skip rescale when no row's max grew (exp(0)=1 exact)
        float nms[4];
        bool grow = false;
#pragma unroll
        for (int r = 0; r < 4; ++r) grow = grow || (mx[r] > mrow[r]);
        if (__ballot(grow) != 0ull) {
#pragma unroll
            for (int r = 0; r < 4; ++r) {
                float nm = fmaxf(mrow[r], mx[r]);
                nms[r] = (nm == -INFINITY) ? 0.f : nm;
                float fr = __expf(mrow[r] - nms[r]);
                mrow[r] = nm;
                lrow[r] *= fr;
#pragma unroll
                for (int ht = 0; ht < 4; ++ht) o[ht][r] *= fr;
            }
        } else {
#pragma unroll
            for (int r = 0; r < 4; ++r) nms[r] = (mrow[r] == -INFINITY) ? 0.f : mrow[r];
        }

        // ---- p = exp(S - m), row sum, l update
#pragma unroll
        for (int t = 0; t < 4; ++t) {
#pragma unroll
            for (int r = 0; r < 4; ++r) S[t][r] = __expf(S[t][r] - nms[r]);
        }
#pragma unroll
        for (int r = 0; r < 4; ++r) {
            float rsum = (S[0][r] + S[1][r]) + (S[2][r] + S[3][r]);
#pragma unroll
            for (int d = 1; d < 16; d <<= 1) rsum += __shfl_xor(rsum, d);
            lrow[r] += rsum;
        }

        // ---- P -> LDS (C/D layout) -> A layout (wave-private pbuf)
#pragma unroll
        for (int t = 0; t < 4; ++t) {
#pragma unroll
            for (int r = 0; r < 4; ++r)
                pbuf[wave][lg * 4 + r][t * 16 + lr] = (f16)S[t][r];
        }
        __builtin_amdgcn_wave_barrier();
        f16x8 pf0 = *(const f16x8*)(&pbuf[wave][lr][lg * 8]);
        f16x8 pf1 = *(const f16x8*)(&pbuf[wave][lr][32 + lg * 8]);

        // ---- PV from vbuf over 64 keys
#pragma unroll
        for (int ht = 0; ht < 4; ++ht) {
            int row = ht * 16 + lr;
            const char* vb = (const char*)vbuf[cur] + row * 128;
            int swz = (row & 7) << 4;
            f16x8 vf0 = *(const f16x8*)(vb + ((lg * 16) ^ swz));
            f16x8 vf1 = *(const f16x8*)(vb + ((64 + lg * 16) ^ swz));
            o[ht] = __builtin_amdgcn_mfma_f32_16x16x32_f16(pf0, vf0, o[ht], 0, 0, 0);
            o[ht] = __builtin_amdgcn_mfma_f32_16x16x32_f16(pf1, vf1, o[ht], 0, 0, 0);
        }
        __builtin_amdgcn_wave_barrier();

        // ---- stage next tile into the other buffer (visible after next barrier)
        if (n + 1 < nsteps) WRITEKV(cur ^ 1);
        cur ^= 1;
    }
#undef LOADKV
#undef WRITEKV

    // ---- write partials (unnormalized o, running m/l)
#pragma unroll
    for (int r = 0; r < 4; ++r) {
        int qt = qrow + lg * 4 + r;
        size_t slot = ((size_t)b * NT + qt) * MAXC + c;
#pragma unroll
        for (int ht = 0; ht < 4; ++ht)
            op[slot * NH + ht * 16 + lr] = (f16)o[ht][r];
        if (lr == 0) {
            float2 v; v.x = mrow[r]; v.y = lrow[r];
            ml[slot] = v;
        }
    }
}

// ---------------- kernel 3: combine split-KV partials --------------------
__global__ __launch_bounds__(256) void combine_kernel(
        const f16* __restrict__ op, const float2* __restrict__ ml,
        float* __restrict__ out) {
    int gid = blockIdx.x * 256 + threadIdx.x;
    int row = gid >> 6;
    int h = gid & 63;
    int q = row & (NT - 1);
    int qi = q >> 6;
    int nc = (qi + 4) >> 2;

    size_t base = (size_t)row * MAXC;
    float2 ml0 = ml[base];
    float M = ml0.x, L = ml0.y;
    float O = (float)op[base * NH + h];
    for (int cc = 1; cc < nc; ++cc) {
        float2 mlc = ml[base + cc];
        if (mlc.x == -INFINITY) continue;
        float oc = (float)op[(base + cc) * NH + h];
        float nM = fmaxf(M, mlc.x);
        float wo = __expf(M - nM), wc = __expf(mlc.x - nM);
        O = O * wo + oc * wc;
        L = L * wo + mlc.y * wc;
        M = nM;
    }
    out[gid] = O / L;
}

extern "C" void kernel_launch(void* const* d_in, const int* in_sizes, int n_in,
                              void* d_out, int out_size, void* d_ws, size_t ws_size,
                              hipStream_t stream) {
    const float* x  = (const float*)d_in[0];
    const float* Wk = (const float*)d_in[1];
    const float* Wq = (const float*)d_in[2];
    const float* Wv = (const float*)d_in[3];
    float* out = (float*)d_out;

    char* ws = (char*)d_ws;
    f16* wt    = (f16*)(ws + OFF_WT);
    f16* Qh    = (f16*)(ws + OFF_QH);
    f16* Kh    = (f16*)(ws + OFF_KH);
    f16* VT    = (f16*)(ws + OFF_VT);
    float2* ml = (float2*)(ws + OFF_ML);
    f16* op    = (f16*)(ws + OFF_OP);

    hipLaunchKernelGGL(wconv_kernel, dim3(48), dim3(256), 0, stream, Wk, Wq, Wv, wt);
    hipLaunchKernelGGL(qkv_proj_kernel, dim3(512), dim3(256), 0, stream, x, wt, Qh, Kh, VT);
    hipLaunchKernelGGL(attn_part_kernel, dim3(NB * CHUNKS_PER_BATCH), dim3(256), 0, stream,
                       Qh, Kh, VT, op, ml);
    hipLaunchKernelGGL(combine_kernel, dim3(NB * NT * NH / 256), dim3(256), 0, stream,
                       op, ml, out);
}